// Round 6
// baseline (92643.872 us; speedup 1.0000x reference)
//
#include <hip/hip_runtime.h>
#include <math.h>

// ESN recurrence: x_t = tanh(w_in*u_t + W x_{t-1}); out[t-washout] = c . x_t
// R6 = MEASUREMENT ROUND. R1-R5: four disjoint in-kernel sync designs all pin
// at ~9.5-10 us/step -> the floor is something they share; split it:
//   (a) esn_sync_only: 2048 iterations of the R5 barrier ALONE (no compute).
//       Its rocprof row = intrinsic in-kernel grid-sync floor.
//   (b) main path = 8192 dependent esn_step launches (graph nodes): the sync
//       is the HW inter-dispatch barrier (AQL release/acquire => plain
//       loads/stores are coherent; zero atomics/fences/spins in the step).
//       W streams from per-XCD L2 (64KB/block, 2MB/XCD resident).
// Headline-total minus probe gives per-dispatch gap cost.

#define H_   2048
#define RPB  8          // rows per block
#define NBLK 256
// ws layout (float idx):
//   [0,2048)      xbuf0        [2048,4096) xbuf1
//   [4096,6144)   c (scatter of w_out by mask)
//   uint idx [8192,9216)   sync_only line counters: 32 lines x 32 uints
//   uint idx [9216,9248)   sync_only global counter
//   uint idx [10240,18432) sync_only flags: 256 private lines x 32 uints
//   [20480, 20480+T*32)    part accumulators: 32 spread slots per step

__global__ void esn_zero(float* __restrict__ p, int n)
{
    int i = blockIdx.x * blockDim.x + threadIdx.x;
    int stride = gridDim.x * blockDim.x;
    for (; i < n; i += stride) p[i] = 0.0f;
}

__global__ __launch_bounds__(1024) void esn_scatter_c(const int* __restrict__ mask,
                                                      const float* __restrict__ w_out,
                                                      float* __restrict__ ws_f, int H)
{
    float* c = ws_f + 2 * H_;
    for (int i = threadIdx.x; i < H; i += blockDim.x)
        atomicAdd(&c[mask[i]], w_out[i]);
}

// ---- one recurrence step; inter-dispatch dependency is the grid barrier ----
__global__ __launch_bounds__(256) void esn_step(const float* __restrict__ u,
                                                const float* __restrict__ w_res,
                                                const float* __restrict__ w_in,
                                                float* __restrict__ out,
                                                float* __restrict__ ws_f,
                                                int k, int washout, int use_part)
{
    __shared__ float xs[H_];
    const int tid  = threadIdx.x;
    const int wave = tid >> 6;
    const int lane = tid & 63;
    const int bid  = blockIdx.x;
    const int r0 = 2 * wave, r1 = 2 * wave + 1;
    const int grow0 = bid * RPB + r0, grow1 = bid * RPB + r1;

    const float* xin  = ws_f + ((k & 1) ? H_ : 0);
    float*       xdst = ws_f + ((k & 1) ? 0 : H_);

    // early scalar loads (overlap with staging/dot)
    float uk = 0.f, win0 = 0.f, win1 = 0.f, c0 = 0.f, c1 = 0.f;
    if (lane == 0) {
        uk   = u[k];
        win0 = w_in[grow0]; win1 = w_in[grow1];
        c0 = ws_f[2 * H_ + grow0]; c1 = ws_f[2 * H_ + grow1];
    }

    // stage x_{t-1} into LDS (plain coalesced loads; AQL acquire made it visible)
#pragma unroll
    for (int i = 0; i < 8; ++i) {
        int j = (i << 8) + tid;
        xs[j] = xin[j];
    }
    __syncthreads();

    const float4* xs4 = (const float4*)xs;
    const float4* w0p = (const float4*)(w_res + (size_t)grow0 * H_);
    const float4* w1p = (const float4*)(w_res + (size_t)grow1 * H_);

    float4 a0 = {0.f,0.f,0.f,0.f}, a1 = {0.f,0.f,0.f,0.f};
#pragma unroll
    for (int c = 0; c < 8; ++c) {
        float4 xv  = xs4[c * 64 + lane];
        float4 wv0 = w0p[c * 64 + lane];   // L2-resident after step 0
        float4 wv1 = w1p[c * 64 + lane];
        a0.x = fmaf(wv0.x, xv.x, a0.x); a0.y = fmaf(wv0.y, xv.y, a0.y);
        a0.z = fmaf(wv0.z, xv.z, a0.z); a0.w = fmaf(wv0.w, xv.w, a0.w);
        a1.x = fmaf(wv1.x, xv.x, a1.x); a1.y = fmaf(wv1.y, xv.y, a1.y);
        a1.z = fmaf(wv1.z, xv.z, a1.z); a1.w = fmaf(wv1.w, xv.w, a1.w);
    }
    float s0 = (a0.x + a0.y) + (a0.z + a0.w);
    float s1 = (a1.x + a1.y) + (a1.z + a1.w);
#pragma unroll
    for (int d = 1; d < 64; d <<= 1) {
        s0 += __shfl_xor(s0, d);
        s1 += __shfl_xor(s1, d);
    }

    if (lane == 0) {
        float z0 = fmaf(win0, uk, s0);
        float z1 = fmaf(win1, uk, s1);
        z0 = fminf(fmaxf(z0, -15.f), 15.f);
        z1 = fminf(fmaxf(z1, -15.f), 15.f);
        float e0 = __expf(2.f * z0), e1 = __expf(2.f * z1);
        float t0 = (e0 - 1.f) / (e0 + 1.f), t1 = (e1 - 1.f) / (e1 + 1.f);
        xdst[grow0] = t0;   // plain stores; AQL release publishes at kernel end
        xdst[grow1] = t1;
        if (k >= washout) {
            float pw = c0 * t0 + c1 * t1;
            if (use_part) atomicAdd(&ws_f[20480 + (size_t)k * 32 + (bid & 7) * 4 + wave], pw);
            else          atomicAdd(&out[k - washout], pw);
        }
    }
}

// ---- diagnostic: the R5 contention-free barrier, ALONE ----
__global__ __launch_bounds__(64) void esn_sync_only(float* __restrict__ ws_f, int iters)
{
    const int lane = threadIdx.x;
    const int bid  = blockIdx.x;
    unsigned* base    = (unsigned*)ws_f;
    unsigned* linecnt = base + 8192 + (bid & 31) * 32;
    unsigned* gcnt    = base + 9216;
    unsigned* flags   = base + 10240;
    unsigned* myflag  = flags + bid * 32;
    int broken = 0;
    for (int k = 0; k < iters; ++k) {
        int pub = 0;
        if (lane == 0) {
            unsigned old = __hip_atomic_fetch_add(linecnt, 1u, __ATOMIC_RELAXED,
                                                  __HIP_MEMORY_SCOPE_AGENT);
            if (old + 1u == (unsigned)(k + 1) * 8u) {
                unsigned g = __hip_atomic_fetch_add(gcnt, 1u, __ATOMIC_RELAXED,
                                                    __HIP_MEMORY_SCOPE_AGENT);
                if (g + 1u == (unsigned)(k + 1) * 32u) pub = 1;
            }
        }
        pub = __shfl(pub, 0);
        if (pub) {
#pragma unroll
            for (int i = 0; i < 4; ++i)
                __hip_atomic_store(flags + (i * 64 + lane) * 32, (unsigned)(k + 1),
                                   __ATOMIC_RELAXED, __HIP_MEMORY_SCOPE_AGENT);
        } else if (!broken) {
            unsigned target = (unsigned)(k + 1);
            int spins = 0;
            for (;;) {
                unsigned v = __hip_atomic_load(myflag, __ATOMIC_RELAXED,
                                               __HIP_MEMORY_SCOPE_AGENT);
                if (v >= target) break;
                if (++spins > 100000) { broken = 1; break; }
            }
        }
        __syncthreads();
    }
}

__global__ void esn_reduce(const float* __restrict__ part, float* __restrict__ out,
                           int out_size, int washout)
{
    int t = blockIdx.x * blockDim.x + threadIdx.x;
    if (t >= out_size) return;
    const float* p = part + (size_t)(t + washout) * 32;
    float s = 0.f;
#pragma unroll
    for (int g = 0; g < 32; ++g) s += p[g];
    out[t] = s;
}

extern "C" void kernel_launch(void* const* d_in, const int* in_sizes, int n_in,
                              void* d_out, int out_size, void* d_ws, size_t ws_size,
                              hipStream_t stream)
{
    const float* u     = (const float*)d_in[0];
    const float* w_res = (const float*)d_in[1];
    const float* w_in  = (const float*)d_in[2];
    const float* w_out = (const float*)d_in[3];
    const int*   mask  = (const int*)d_in[4];
    int T = in_sizes[0];
    int H = in_sizes[2];
    int washout = T - out_size;
    float* out  = (float*)d_out;
    float* ws_f = (float*)d_ws;

    size_t need = (size_t)(20480 + (size_t)T * 32) * 4;
    int use_part = (ws_size >= need) ? 1 : 0;
    int zero_n = use_part ? (20480 + T * 32) : 20480;

    hipLaunchKernelGGL(esn_zero, dim3(64), dim3(256), 0, stream, ws_f, zero_n);
    if (!use_part)
        hipLaunchKernelGGL(esn_zero, dim3(32), dim3(256), 0, stream, out, out_size);
    hipLaunchKernelGGL(esn_scatter_c, dim3(1), dim3(1024), 0, stream, mask, w_out, ws_f, H);

    // ---- probe: intrinsic in-kernel barrier floor (2048 iterations) ----
    {
        int iters = 2048;
        void* args[] = { (void*)&ws_f, (void*)&iters };
        hipError_t e = hipLaunchCooperativeKernel((const void*)esn_sync_only,
                                                  dim3(NBLK), dim3(64), args, 0, stream);
        if (e != hipSuccess)
            hipLaunchKernelGGL(esn_sync_only, dim3(NBLK), dim3(64), 0, stream, ws_f, iters);
    }

    // ---- main path: one dispatch per step; HW inter-dispatch barrier ----
    for (int k = 0; k < T; ++k)
        hipLaunchKernelGGL(esn_step, dim3(NBLK), dim3(256), 0, stream,
                           u, w_res, w_in, out, ws_f, k, washout, use_part);

    if (use_part)
        hipLaunchKernelGGL(esn_reduce, dim3((out_size + 255) / 256), dim3(256), 0, stream,
                           ws_f + 20480, out, out_size, washout);
}

// Round 7
// 40905.194 us; speedup vs baseline: 2.2648x; 2.2648x over previous
//
#include <hip/hip_runtime.h>
#include <math.h>

// ESN recurrence: x_t = tanh(w_in*u_t + W x_{t-1}); out[t-washout] = c . x_t
// R7: ZERO atomic RMWs on the critical path (and none in the step at all).
// R5 post-mortem arithmetic: its gcnt line absorbed 32 fetch_adds/step in a
// burst; far-atomic same-line RMWs serialize (~200-500cy each) -> 2.7-6.4us,
// plus linecnt bursts and 256 background readout atomicAdds/step at the same
// far-atomic units. That is the ~10us floor. Multi-launch (R6) measured at
// ~9-11us/dispatch -> dead end.
// New barrier: arrive = block stores epoch to its PRIVATE line; block 0's
// wave 0 sweeps all 256 lines (sole reader); publish = 64 lanes store epoch
// to 256 PRIVATE flag lines; each block polls only its own. Readout = plain
// store to part[k*256+bid], reduced in an epilogue kernel.

#define H_   2048
#define RPB  8          // rows per block
#define NBLK 256
// ws layout (32-bit idx):
//   float [0,2048)     xbuf0
//   float [2048,4096)  xbuf1
//   float [4096,6144)  c (scatter of w_out by mask)
//   uint  [8192,16384)  arrival lines: 256 x 32 uints (128 B stride)
//   uint  [16384,24576) flag lines:    256 x 32 uints
//   float [24576, 24576+T*256)  part: per-step per-block partial (plain store)

__global__ void esn_zero(float* __restrict__ p, int n)
{
    int i = blockIdx.x * blockDim.x + threadIdx.x;
    int stride = gridDim.x * blockDim.x;
    for (; i < n; i += stride) p[i] = 0.0f;
}

__global__ __launch_bounds__(1024) void esn_scatter_c(const int* __restrict__ mask,
                                                      const float* __restrict__ w_out,
                                                      float* __restrict__ ws_f, int H)
{
    float* c = ws_f + 2 * H_;
    for (int i = threadIdx.x; i < H; i += blockDim.x)
        atomicAdd(&c[mask[i]], w_out[i]);
}

__global__ __launch_bounds__(256) void esn_run(const float* __restrict__ u,
                                               const float* __restrict__ w_res,
                                               const float* __restrict__ w_in,
                                               float* __restrict__ out,
                                               float* __restrict__ ws_f,
                                               int T, int washout, int use_part)
{
    __shared__ float Wlds[RPB * H_];   // 64 KB
    __shared__ float xs[H_];           // 8 KB staged x_{t-1}
    __shared__ float psum[4];          // per-wave readout partials

    const int tid  = threadIdx.x;
    const int wave = tid >> 6;
    const int lane = tid & 63;
    const int bid  = blockIdx.x;
    const int r0 = 2 * wave, r1 = 2 * wave + 1;
    const int grow0 = bid * RPB + r0, grow1 = bid * RPB + r1;

    // ---- one-time: stage this block's 8 W rows into LDS (coalesced) ----
    {
        const float4* src = (const float4*)(w_res + (size_t)bid * RPB * H_);
        float4* dst = (float4*)Wlds;
        for (int i = tid; i < RPB * H_ / 4; i += 256) dst[i] = src[i];
    }
    float win0 = 0.f, win1 = 0.f, c0 = 0.f, c1 = 0.f;
    if (lane == 0) {
        win0 = w_in[grow0]; win1 = w_in[grow1];
        c0 = ws_f[2 * H_ + grow0]; c1 = ws_f[2 * H_ + grow1];
    }

    float* buf0 = ws_f;
    float* buf1 = ws_f + H_;
    unsigned* arr    = (unsigned*)(ws_f + 8192);
    unsigned* flags  = (unsigned*)(ws_f + 16384);
    unsigned* myarr  = arr   + bid * 32;   // private: 1 writer (me), 1 reader (detector)
    unsigned* myflag = flags + bid * 32;   // private: 1 writer (detector), 1 reader (me)
    float* part = ws_f + 24576;
    const int detector = (bid == 0);

    const float4* w0p = (const float4*)(Wlds + r0 * H_);
    const float4* w1p = (const float4*)(Wlds + r1 * H_);
    const float4* xs4 = (const float4*)xs;

    int broken = 0;
    float u_next = u[0];
    __syncthreads();   // Wlds ready

    for (int k = 0; k < T; ++k) {
        // ---- stage x_{t-1} from L3 into LDS (sc1 relaxed agent loads) ----
        const float* xsrc = (k & 1) ? buf1 : buf0;
        float*       xdst = (k & 1) ? buf0 : buf1;
#pragma unroll
        for (int i = 0; i < 8; ++i) {
            int j = (i << 8) + tid;
            xs[j] = __hip_atomic_load(xsrc + j, __ATOMIC_RELAXED,
                                      __HIP_MEMORY_SCOPE_AGENT);
        }
        float uk = u_next;
        if (k + 1 < T) u_next = u[k + 1];
        __syncthreads();

        // ---- dot: wave owns rows r0,r1; lanes sweep 2048 as float4 ----
        float4 a0 = {0.f,0.f,0.f,0.f}, a1 = {0.f,0.f,0.f,0.f};
#pragma unroll
        for (int c = 0; c < 8; ++c) {
            float4 xv  = xs4[c * 64 + lane];
            float4 wv0 = w0p[c * 64 + lane];
            float4 wv1 = w1p[c * 64 + lane];
            a0.x = fmaf(wv0.x, xv.x, a0.x); a0.y = fmaf(wv0.y, xv.y, a0.y);
            a0.z = fmaf(wv0.z, xv.z, a0.z); a0.w = fmaf(wv0.w, xv.w, a0.w);
            a1.x = fmaf(wv1.x, xv.x, a1.x); a1.y = fmaf(wv1.y, xv.y, a1.y);
            a1.z = fmaf(wv1.z, xv.z, a1.z); a1.w = fmaf(wv1.w, xv.w, a1.w);
        }
        float s0 = (a0.x + a0.y) + (a0.z + a0.w);
        float s1 = (a1.x + a1.y) + (a1.z + a1.w);
#pragma unroll
        for (int d = 1; d < 64; d <<= 1) {
            s0 += __shfl_xor(s0, d);
            s1 += __shfl_xor(s1, d);
        }

        if (lane == 0) {
            float z0 = fmaf(win0, uk, s0);
            float z1 = fmaf(win1, uk, s1);
            z0 = fminf(fmaxf(z0, -15.f), 15.f);
            z1 = fminf(fmaxf(z1, -15.f), 15.f);
            float e0 = __expf(2.f * z0), e1 = __expf(2.f * z1);
            float t0 = (e0 - 1.f) / (e0 + 1.f), t1 = (e1 - 1.f) / (e1 + 1.f);
            __hip_atomic_store(xdst + grow0, t0, __ATOMIC_RELAXED,
                               __HIP_MEMORY_SCOPE_AGENT);
            __hip_atomic_store(xdst + grow1, t1, __ATOMIC_RELAXED,
                               __HIP_MEMORY_SCOPE_AGENT);
            psum[wave] = c0 * t0 + c1 * t1;
        }
        asm volatile("s_waitcnt vmcnt(0)" ::: "memory");  // x stores at L3
        __syncthreads();                                  // all waves drained

        if (wave == 0) {
            // ---- arrive: plain private-line store (no RMW) ----
            if (lane == 0)
                __hip_atomic_store(myarr, (unsigned)(k + 1), __ATOMIC_RELAXED,
                                   __HIP_MEMORY_SCOPE_AGENT);
            // ---- readout partial: plain private store, off critical path ----
            if (lane == 0) {
                float pw = (psum[0] + psum[1]) + (psum[2] + psum[3]);
                if (use_part) part[(size_t)k * NBLK + bid] = pw;
                else if (k >= washout) atomicAdd(&out[k - washout], pw);
            }

            if (detector) {
                // ---- sweep all 256 arrival lines (sole reader of each) ----
                unsigned target = (unsigned)(k + 1);
                if (!broken) {
                    int spins = 0;
                    for (;;) {
                        unsigned v0 = __hip_atomic_load(arr + (lane)       * 32, __ATOMIC_RELAXED, __HIP_MEMORY_SCOPE_AGENT);
                        unsigned v1 = __hip_atomic_load(arr + (lane +  64) * 32, __ATOMIC_RELAXED, __HIP_MEMORY_SCOPE_AGENT);
                        unsigned v2 = __hip_atomic_load(arr + (lane + 128) * 32, __ATOMIC_RELAXED, __HIP_MEMORY_SCOPE_AGENT);
                        unsigned v3 = __hip_atomic_load(arr + (lane + 192) * 32, __ATOMIC_RELAXED, __HIP_MEMORY_SCOPE_AGENT);
                        if (__all(v0 >= target && v1 >= target &&
                                  v2 >= target && v3 >= target)) break;
                        if (++spins > 1000000) { broken = 1; break; }
                    }
                }
                // ---- publish to 256 private flag lines (fire and forget) ----
#pragma unroll
                for (int i = 0; i < 4; ++i)
                    __hip_atomic_store(flags + (lane + i * 64) * 32, target,
                                       __ATOMIC_RELAXED, __HIP_MEMORY_SCOPE_AGENT);
            } else if (!broken) {
                // ---- wait: poll ONLY my private flag line ----
                unsigned target = (unsigned)(k + 1);
                int spins = 0;
                for (;;) {
                    unsigned v = __hip_atomic_load(myflag, __ATOMIC_RELAXED,
                                                   __HIP_MEMORY_SCOPE_AGENT);
                    if (v >= target) break;
                    if (++spins > 4000000) { broken = 1; break; }
                    __builtin_amdgcn_s_sleep(1);
                }
            }
        }
        __syncthreads();
    }
}

// sum the 256 per-block partials for each output step (one wave per t)
__global__ __launch_bounds__(256) void esn_reduce(const float* __restrict__ part,
                                                  float* __restrict__ out,
                                                  int out_size, int washout)
{
    int wv = threadIdx.x >> 6, lane = threadIdx.x & 63;
    int t = blockIdx.x * 4 + wv;
    if (t >= out_size) return;
    const float4* p = (const float4*)(part + (size_t)(t + washout) * NBLK);
    float4 v = p[lane];
    float s = (v.x + v.y) + (v.z + v.w);
#pragma unroll
    for (int d = 1; d < 64; d <<= 1) s += __shfl_xor(s, d);
    if (lane == 0) out[t] = s;
}

extern "C" void kernel_launch(void* const* d_in, const int* in_sizes, int n_in,
                              void* d_out, int out_size, void* d_ws, size_t ws_size,
                              hipStream_t stream)
{
    const float* u     = (const float*)d_in[0];
    const float* w_res = (const float*)d_in[1];
    const float* w_in  = (const float*)d_in[2];
    const float* w_out = (const float*)d_in[3];
    const int*   mask  = (const int*)d_in[4];
    int T = in_sizes[0];
    int H = in_sizes[2];
    int washout = T - out_size;
    float* out  = (float*)d_out;
    float* ws_f = (float*)d_ws;

    size_t need = (size_t)(24576 + (size_t)T * NBLK) * 4;
    int use_part = (ws_size >= need) ? 1 : 0;

    hipLaunchKernelGGL(esn_zero, dim3(64), dim3(256), 0, stream, ws_f, 24576);
    if (!use_part)
        hipLaunchKernelGGL(esn_zero, dim3(32), dim3(256), 0, stream, out, out_size);
    hipLaunchKernelGGL(esn_scatter_c, dim3(1), dim3(1024), 0, stream, mask, w_out, ws_f, H);

    void* args[] = { (void*)&u, (void*)&w_res, (void*)&w_in, (void*)&out,
                     (void*)&ws_f, (void*)&T, (void*)&washout, (void*)&use_part };
    hipError_t e = hipLaunchCooperativeKernel((const void*)esn_run,
                                              dim3(NBLK), dim3(256),
                                              args, 0, stream);
    if (e != hipSuccess) {
        hipLaunchKernelGGL(esn_run, dim3(NBLK), dim3(256), 0, stream,
                           u, w_res, w_in, out, ws_f, T, washout, use_part);
    }
    if (use_part)
        hipLaunchKernelGGL(esn_reduce, dim3((out_size + 3) / 4), dim3(256), 0, stream,
                           ws_f + 24576, out, out_size, washout);
}

// Round 8
// 40727.286 us; speedup vs baseline: 2.2747x; 1.0044x over previous
//
#include <hip/hip_runtime.h>
#include <math.h>

// ESN recurrence: x_t = tanh(w_in*u_t + W x_{t-1}); out[t-washout] = c . x_t
// R8: NO barrier at all. Each x element is an 8-byte (value, epoch) pair
// stored with one relaxed agent-scope store; consumers stage x_k by polling
// the pairs until tag==k. The x store itself is the arrival signal -- the
// R7 4-hop chain (arrive->detect->publish->observe, each an L3 RTT) collapses
// to a single producer->consumer visibility edge. Double buffering is safe:
// a block writes epoch k+2 over epoch-k pairs only after observing all k+1
// tags, and any k+1 store data-depends on that block having fully staged
// epoch k (its dot consumed every pair).
// Readout: plain per-block store part[k*256+bid], epilogue reduce. No RMWs.

#define H_   2048
#define RPB  8          // rows per block
#define NBLK 256
typedef unsigned long long ull;
// ws layout (float idx):
//   ull  [0,4096)      pair buffers: buf0 = pairs[0..2048), buf1 = pairs[2048..4096)
//                      (= float idx [0,8192))
//   float [8192,10240)  c (scatter of w_out by mask)
//   float [10240, 10240+T*256)  part: per-step per-block partial (plain store)

__global__ void esn_zero(float* __restrict__ p, int n)
{
    int i = blockIdx.x * blockDim.x + threadIdx.x;
    int stride = gridDim.x * blockDim.x;
    for (; i < n; i += stride) p[i] = 0.0f;
}

__global__ __launch_bounds__(1024) void esn_scatter_c(const int* __restrict__ mask,
                                                      const float* __restrict__ w_out,
                                                      float* __restrict__ ws_f, int H)
{
    float* c = ws_f + 8192;
    for (int i = threadIdx.x; i < H; i += blockDim.x)
        atomicAdd(&c[mask[i]], w_out[i]);
}

__global__ __launch_bounds__(256) void esn_run(const float* __restrict__ u,
                                               const float* __restrict__ w_res,
                                               const float* __restrict__ w_in,
                                               float* __restrict__ out,
                                               float* __restrict__ ws_f,
                                               int T, int washout, int use_part)
{
    __shared__ float Wlds[RPB * H_];   // 64 KB
    __shared__ float xs[H_];           // 8 KB staged x_{t-1}
    __shared__ float psum[4];

    const int tid  = threadIdx.x;
    const int wave = tid >> 6;
    const int lane = tid & 63;
    const int bid  = blockIdx.x;
    const int r0 = 2 * wave, r1 = 2 * wave + 1;
    const int grow0 = bid * RPB + r0, grow1 = bid * RPB + r1;

    // ---- one-time: stage this block's 8 W rows into LDS (coalesced) ----
    {
        const float4* src = (const float4*)(w_res + (size_t)bid * RPB * H_);
        float4* dst = (float4*)Wlds;
        for (int i = tid; i < RPB * H_ / 4; i += 256) dst[i] = src[i];
    }
    float win0 = 0.f, win1 = 0.f, c0 = 0.f, c1 = 0.f;
    if (lane == 0) {
        win0 = w_in[grow0]; win1 = w_in[grow1];
        c0 = ws_f[8192 + grow0]; c1 = ws_f[8192 + grow1];
    }

    ull* pairs = (ull*)ws_f;           // [0,2048) epoch-even, [2048,4096) epoch-odd
    float* part = ws_f + 10240;

    const float4* w0p = (const float4*)(Wlds + r0 * H_);
    const float4* w1p = (const float4*)(Wlds + r1 * H_);
    const float4* xs4 = (const float4*)xs;

    float u_next = u[0];
    __syncthreads();   // Wlds ready

    for (int k = 0; k < T; ++k) {
        const ull* sp = pairs + (k & 1) * H_;          // holds epoch k
        ull*       dp = pairs + ((k + 1) & 1) * H_;    // will hold epoch k+1
        float uk = u_next;
        if (k + 1 < T) u_next = u[k + 1];

        // ---- stage x_k: batch-load 8 pairs, then spin only on stale ones ----
        ull pv[8];
#pragma unroll
        for (int i = 0; i < 8; ++i)
            pv[i] = __hip_atomic_load(sp + (i << 8) + tid, __ATOMIC_RELAXED,
                                      __HIP_MEMORY_SCOPE_AGENT);
#pragma unroll
        for (int i = 0; i < 8; ++i) {
            int spins = 0;
            while ((unsigned)(pv[i] >> 32) != (unsigned)k) {
                pv[i] = __hip_atomic_load(sp + (i << 8) + tid, __ATOMIC_RELAXED,
                                          __HIP_MEMORY_SCOPE_AGENT);
                if (++spins > 2000000) break;   // failsafe: never hang
            }
            xs[(i << 8) + tid] = __uint_as_float((unsigned)pv[i]);
        }
        __syncthreads();

        // ---- dot: wave owns rows r0,r1; lanes sweep 2048 as float4 ----
        float4 a0 = {0.f,0.f,0.f,0.f}, a1 = {0.f,0.f,0.f,0.f};
#pragma unroll
        for (int c = 0; c < 8; ++c) {
            float4 xv  = xs4[c * 64 + lane];
            float4 wv0 = w0p[c * 64 + lane];
            float4 wv1 = w1p[c * 64 + lane];
            a0.x = fmaf(wv0.x, xv.x, a0.x); a0.y = fmaf(wv0.y, xv.y, a0.y);
            a0.z = fmaf(wv0.z, xv.z, a0.z); a0.w = fmaf(wv0.w, xv.w, a0.w);
            a1.x = fmaf(wv1.x, xv.x, a1.x); a1.y = fmaf(wv1.y, xv.y, a1.y);
            a1.z = fmaf(wv1.z, xv.z, a1.z); a1.w = fmaf(wv1.w, xv.w, a1.w);
        }
        float s0 = (a0.x + a0.y) + (a0.z + a0.w);
        float s1 = (a1.x + a1.y) + (a1.z + a1.w);
#pragma unroll
        for (int d = 1; d < 64; d <<= 1) {
            s0 += __shfl_xor(s0, d);
            s1 += __shfl_xor(s1, d);
        }

        if (lane == 0) {
            float z0 = fmaf(win0, uk, s0);
            float z1 = fmaf(win1, uk, s1);
            z0 = fminf(fmaxf(z0, -15.f), 15.f);
            z1 = fminf(fmaxf(z1, -15.f), 15.f);
            float e0 = __expf(2.f * z0), e1 = __expf(2.f * z1);
            float t0 = (e0 - 1.f) / (e0 + 1.f), t1 = (e1 - 1.f) / (e1 + 1.f);
            ull p0 = ((ull)(unsigned)(k + 1) << 32) | (ull)__float_as_uint(t0);
            ull p1 = ((ull)(unsigned)(k + 1) << 32) | (ull)__float_as_uint(t1);
            // fire-and-forget: visibility of these stores IS the sync protocol
            __hip_atomic_store(dp + grow0, p0, __ATOMIC_RELAXED,
                               __HIP_MEMORY_SCOPE_AGENT);
            __hip_atomic_store(dp + grow1, p1, __ATOMIC_RELAXED,
                               __HIP_MEMORY_SCOPE_AGENT);
            psum[wave] = c0 * t0 + c1 * t1;
        }
        __syncthreads();   // psum ready; xs reads done (safe to restage)

        if (tid == 0) {    // off critical path; plain store, no RMW
            float pw = (psum[0] + psum[1]) + (psum[2] + psum[3]);
            if (use_part) part[(size_t)k * NBLK + bid] = pw;
            else if (k >= washout) atomicAdd(&out[k - washout], pw);
        }
    }
}

// sum the 256 per-block partials for each output step (one wave per t)
__global__ __launch_bounds__(256) void esn_reduce(const float* __restrict__ part,
                                                  float* __restrict__ out,
                                                  int out_size, int washout)
{
    int wv = threadIdx.x >> 6, lane = threadIdx.x & 63;
    int t = blockIdx.x * 4 + wv;
    if (t >= out_size) return;
    const float4* p = (const float4*)(part + (size_t)(t + washout) * NBLK);
    float4 v = p[lane];
    float s = (v.x + v.y) + (v.z + v.w);
#pragma unroll
    for (int d = 1; d < 64; d <<= 1) s += __shfl_xor(s, d);
    if (lane == 0) out[t] = s;
}

extern "C" void kernel_launch(void* const* d_in, const int* in_sizes, int n_in,
                              void* d_out, int out_size, void* d_ws, size_t ws_size,
                              hipStream_t stream)
{
    const float* u     = (const float*)d_in[0];
    const float* w_res = (const float*)d_in[1];
    const float* w_in  = (const float*)d_in[2];
    const float* w_out = (const float*)d_in[3];
    const int*   mask  = (const int*)d_in[4];
    int T = in_sizes[0];
    int H = in_sizes[2];
    int washout = T - out_size;
    float* out  = (float*)d_out;
    float* ws_f = (float*)d_ws;

    size_t need = (size_t)(10240 + (size_t)T * NBLK) * 4;
    int use_part = (ws_size >= need) ? 1 : 0;

    // zero pair buffers (epoch 0 = initial x=0 state) + c
    hipLaunchKernelGGL(esn_zero, dim3(64), dim3(256), 0, stream, ws_f, 10240);
    if (!use_part)
        hipLaunchKernelGGL(esn_zero, dim3(32), dim3(256), 0, stream, out, out_size);
    hipLaunchKernelGGL(esn_scatter_c, dim3(1), dim3(1024), 0, stream, mask, w_out, ws_f, H);

    void* args[] = { (void*)&u, (void*)&w_res, (void*)&w_in, (void*)&out,
                     (void*)&ws_f, (void*)&T, (void*)&washout, (void*)&use_part };
    hipError_t e = hipLaunchCooperativeKernel((const void*)esn_run,
                                              dim3(NBLK), dim3(256),
                                              args, 0, stream);
    if (e != hipSuccess) {
        hipLaunchKernelGGL(esn_run, dim3(NBLK), dim3(256), 0, stream,
                           u, w_res, w_in, out, ws_f, T, washout, use_part);
    }
    if (use_part)
        hipLaunchKernelGGL(esn_reduce, dim3((out_size + 3) / 4), dim3(256), 0, stream,
                           ws_f + 10240, out, out_size, washout);
}